// Round 11
// baseline (284.068 us; speedup 1.0000x reference)
//
#include <hip/hip_runtime.h>
#include <stdint.h>

#define BB 4
#define SEQ 2048
#define DMODEL 1024
#define NHEAD 16
#define HDIM 64
#define INTER 1024
// attn scale folded into q at GEMM1 epilogue, with log2(e) so softmax is exp2:
// 0.03125 * 1.4426950408889634
#define QSCALE 0.045084220027780106f

#if __has_builtin(__builtin_amdgcn_exp2f)
#define EXP2F(x) __builtin_amdgcn_exp2f(x)
#else
#define EXP2F(x) exp2f(x)
#endif

typedef unsigned short u16;
typedef __attribute__((ext_vector_type(4))) unsigned short u16x4;
typedef __attribute__((ext_vector_type(4))) short s16x4;
typedef __attribute__((ext_vector_type(8))) short s16x8;   // 8 bf16 (4 VGPRs) MFMA A/B frag
typedef __attribute__((ext_vector_type(4))) float f32x4;
typedef __attribute__((ext_vector_type(16))) float f32x16; // 32x32 MFMA C/D frag
typedef __attribute__((ext_vector_type(4))) unsigned int u32x4;

__device__ __forceinline__ u16 f2bf(float f) {
  unsigned int u = __float_as_uint(f);
  u += 0x7FFFu + ((u >> 16) & 1u);   // RNE
  return (u16)(u >> 16);
}

// pack 2 fp32 -> 2 bf16 in one dword (lo = a, hi = b)
#if __has_builtin(__builtin_amdgcn_cvt_pk_bf16_f32)
typedef __attribute__((ext_vector_type(2))) __bf16 bf16x2_t;
__device__ __forceinline__ unsigned int pk2bf(float a, float b) {
  bf16x2_t r = __builtin_amdgcn_cvt_pk_bf16_f32(a, b);
  return *reinterpret_cast<unsigned int*>(&r);
}
#else
__device__ __forceinline__ unsigned int pk2bf(float a, float b) {
  return (unsigned int)f2bf(a) | ((unsigned int)f2bf(b) << 16);
}
#endif

// async global->LDS, 16B per lane; LDS dest is wave-uniform base + lane*16
__device__ __forceinline__ void async16(const u16* g, u16* l) {
  __builtin_amdgcn_global_load_lds((__attribute__((address_space(1))) void*)(void*)(g),
                                   (__attribute__((address_space(3))) void*)(l),
                                   16, 0, 0);
}

// Redistribute P into the two PV B-fragments fully in-register.
// Correctness-verified in the harness (absmax identical to the LDS path).
__device__ __forceinline__ void make_pb(const unsigned int* cc, int half,
                                        s16x8& pb0, s16x8& pb1) {
#if __has_builtin(__builtin_amdgcn_permlane32_swap)
  (void)half;
  auto r02 = __builtin_amdgcn_permlane32_swap(cc[0], cc[2], false, false);
  auto r13 = __builtin_amdgcn_permlane32_swap(cc[1], cc[3], false, false);
  auto r46 = __builtin_amdgcn_permlane32_swap(cc[4], cc[6], false, false);
  auto r57 = __builtin_amdgcn_permlane32_swap(cc[5], cc[7], false, false);
  u32x4 w0 = {(unsigned)r02[0], (unsigned)r13[0], (unsigned)r02[1], (unsigned)r13[1]};
  u32x4 w1 = {(unsigned)r46[0], (unsigned)r57[0], (unsigned)r46[1], (unsigned)r57[1]};
#else
  unsigned x0 = __shfl_xor((int)cc[0], 32, 64), x1 = __shfl_xor((int)cc[1], 32, 64);
  unsigned x2 = __shfl_xor((int)cc[2], 32, 64), x3 = __shfl_xor((int)cc[3], 32, 64);
  unsigned x4 = __shfl_xor((int)cc[4], 32, 64), x5 = __shfl_xor((int)cc[5], 32, 64);
  unsigned x6 = __shfl_xor((int)cc[6], 32, 64), x7 = __shfl_xor((int)cc[7], 32, 64);
  u32x4 w0 = {half ? x2 : cc[0], half ? x3 : cc[1],
              half ? cc[2] : x0, half ? cc[3] : x1};
  u32x4 w1 = {half ? x6 : cc[4], half ? x7 : cc[5],
              half ? cc[6] : x4, half ? cc[7] : x5};
#endif
  pb0 = *reinterpret_cast<s16x8*>(&w0);
  pb1 = *reinterpret_cast<s16x8*>(&w1);
}

// ------------- prep v2a: cast features, 32 B per thread -------------
__global__ __launch_bounds__(256) void featcast(const float* __restrict__ f,
                                                u16* __restrict__ Xb) {
  const int i = (blockIdx.x * 256 + threadIdx.x) * 8;
  f32x4 a = *reinterpret_cast<const f32x4*>(f + i);
  f32x4 b = *reinterpret_cast<const f32x4*>(f + i + 4);
  uint4 o;
  o.x = pk2bf(a[0], a[1]);
  o.y = pk2bf(a[2], a[3]);
  o.z = pk2bf(b[0], b[1]);
  o.w = pk2bf(b[2], b[3]);
  *reinterpret_cast<uint4*>(Xb + i) = o;
}

// ------------- prep v2b: transpose-cast both weights, 64x64 tiles -------------
__global__ __launch_bounds__(256) void wtrans(
    const float* __restrict__ wqkv, const float* __restrict__ wout,
    u16* __restrict__ WqkvT, u16* __restrict__ WoutT) {
  __shared__ u16 tile[64][65];
  int t = blockIdx.x;
  const float* src; u16* dst; int rows, cols, bx, by;
  if (t < 768) {                          // W_qkv: [1024][3072] -> [3072][1024]
    src = wqkv; dst = WqkvT; rows = DMODEL; cols = 3 * INTER;
    bx = t % 48; by = t / 48;
  } else {                                // W_out: [1024][1024] -> [1024][1024]
    t -= 768;
    src = wout; dst = WoutT; rows = INTER; cols = DMODEL;
    bx = t & 15; by = t >> 4;
  }
  const int c0 = bx * 64, r0 = by * 64;
  const int tx = threadIdx.x & 63, ty = threadIdx.x >> 6;
  #pragma unroll
  for (int i = ty; i < 64; i += 4)
    tile[i][tx] = f2bf(src[(size_t)(r0 + i) * cols + c0 + tx]);
  __syncthreads();
  #pragma unroll
  for (int i = ty; i < 64; i += 4)
    dst[(size_t)(c0 + i) * rows + r0 + tx] = tile[tx][i];
}

// ---------------- bf16 GEMM, B-transposed input (round-6, known-good) ----------------
#define GCOMP(ABUF, BBUF)                                                         \
  {                                                                               \
    s16x8 af[4], bf[4];                                                           \
    _Pragma("unroll")                                                             \
    for (int t = 0; t < 4; t++) {                                                 \
      af[t] = *reinterpret_cast<const s16x8*>(&ABUF[(wr + t * 16 + r) * 32 + q8]); \
      bf[t] = *reinterpret_cast<const s16x8*>(&BBUF[(wc + t * 16 + r) * 32 + q8]); \
    }                                                                             \
    _Pragma("unroll")                                                             \
    for (int i = 0; i < 4; i++)                                                   \
      _Pragma("unroll")                                                           \
      for (int j = 0; j < 4; j++)                                                 \
        acc[i][j] = __builtin_amdgcn_mfma_f32_16x16x32_bf16(af[i], bf[j], acc[i][j], 0, 0, 0); \
  }

template <int MODE>
__global__ __launch_bounds__(256, 2) void gemm_bt(
    const u16* __restrict__ A, const u16* __restrict__ BT,
    float* __restrict__ Cf, u16* __restrict__ Qb, u16* __restrict__ Kp,
    u16* __restrict__ Vp, int K, int ldc) {
  __shared__ u16 As[2][128 * 32];
  __shared__ u16 Bs[2][128 * 32];
  const int tid = threadIdx.x;
  const int wave = tid >> 6, lane = tid & 63;
  const int row0 = blockIdx.y * 128, col0 = blockIdx.x * 128;
  const int wr = (wave >> 1) * 64, wc = (wave & 1) * 64;
  const int r = lane & 15, q8 = (lane >> 4) * 8;

  f32x4 acc[4][4] = {};

  const int sRow = lane >> 2, sK = (lane & 3) * 8;
  const u16* Ag0 = A + (size_t)(row0 + wave * 32 + sRow) * K + sK;
  const u16* Ag1 = Ag0 + (size_t)16 * K;
  const u16* Bg0 = BT + (size_t)(col0 + wave * 32 + sRow) * K + sK;
  const u16* Bg1 = Bg0 + (size_t)16 * K;
  u16* Al0a = &As[0][wave * 1024]; u16* Al1a = Al0a + 512;
  u16* Bl0a = &Bs[0][wave * 1024]; u16* Bl1a = Bl0a + 512;
  u16* Al0b = &As[1][wave * 1024]; u16* Al1b = Al0b + 512;
  u16* Bl0b = &Bs[1][wave * 1024]; u16* Bl1b = Bl0b + 512;

  // prologue: stage K-tile 0 into buffer A
  async16(Ag0, Al0a);
  async16(Ag1, Al1a);
  async16(Bg0, Bl0a);
  async16(Bg1, Bl1a);
  __syncthreads();

  for (int k0 = 0; k0 < K; k0 += 64) {
    if (k0 + 32 < K) {
      async16(Ag0 + k0 + 32, Al0b);
      async16(Ag1 + k0 + 32, Al1b);
      async16(Bg0 + k0 + 32, Bl0b);
      async16(Bg1 + k0 + 32, Bl1b);
    }
    GCOMP(As[0], Bs[0])
    __syncthreads();
    if (k0 + 64 < K) {
      async16(Ag0 + k0 + 64, Al0a);
      async16(Ag1 + k0 + 64, Al1a);
      async16(Bg0 + k0 + 64, Bl0a);
      async16(Bg1 + k0 + 64, Bl1a);
    }
    GCOMP(As[1], Bs[1])
    __syncthreads();
  }

  const int quad = lane >> 4;
  #pragma unroll
  for (int i = 0; i < 4; i++) {
    const int n = row0 + wr + i * 16 + quad * 4;   // global row for regs 0..3
    const int b = n >> 11, nn = n & (SEQ - 1);
    #pragma unroll
    for (int j = 0; j < 4; j++) {
      const int gc = col0 + wc + j * 16 + r;       // wave-uniform region
      if (MODE == 1) {
        #pragma unroll
        for (int reg = 0; reg < 4; reg++)
          Cf[(size_t)(n + reg) * ldc + gc] = acc[i][j][reg];
      } else if (gc < INTER) {                     // q: row-major, scaled
        size_t base = (size_t)n * INTER + gc;
        #pragma unroll
        for (int reg = 0; reg < 4; reg++)
          Qb[base + (size_t)reg * INTER] = f2bf(acc[i][j][reg] * QSCALE);
      } else if (gc < 2 * INTER) {                 // k -> Kp packed
        int dim = gc - INTER, h = dim >> 6, d = dim & 63;
        int bh = b * NHEAD + h;
        size_t base = (((size_t)(bh * 64 + (nn >> 5)) * 4 + (d >> 4)) * 64 +
                       ((((d >> 3) & 1) << 5) | (nn & 31))) * 8 + (d & 7);
        #pragma unroll
        for (int reg = 0; reg < 4; reg++)
          Kp[base + reg * 8] = f2bf(acc[i][j][reg]);
      } else {                                     // v -> Vp packed, b64 store
        int dim = gc - 2 * INTER, h = dim >> 6, d = dim & 63;
        int bh = b * NHEAD + h;
        size_t base = ((((size_t)(bh * 64 + (nn >> 5)) * 2 + ((nn >> 4) & 1)) * 2 +
                        (d >> 5)) * 64 +
                       ((((nn >> 3) & 1) << 5) | (d & 31))) * 8 + (nn & 7);
        uint2 pk;
        pk.x = pk2bf(acc[i][j][0], acc[i][j][1]);
        pk.y = pk2bf(acc[i][j][2], acc[i][j][3]);
        *reinterpret_cast<uint2*>(Vp + base) = pk;
      }
    }
  }
}

// ---------------- flash-style attention, LDS-shared K/V (v11) ----------------
// Diagnosis (r10): 95.5us/64 steps = ~3560 cyc/step vs ~600-cyc theoretical
// chain -- load-service bound: 4096 waves each privately stream 512 KB K/V
// from L2 (2.1 GB, ~50% of per-XCD L2 BW, at 200-500 cyc latency). Fix: 4
// waves per block SHARE each K/V j-block through LDS (identity-map staging of
// the packed layout; traffic 4x down, loads become 64-cyc ds_reads), keeping
// 32 q-rows/wave (~150 VGPR, no spill) and the T15 S-pipeline (K(j+1) is in
// LDS since step j-1, so QK(j+1) still issues before softmax(j)).
// Sync: ONE __syncthreads per step. Its vmcnt(0)+lgkmcnt(0) drain is exactly
// the required semantics: staged data must land before next step reads it
// (staged at step start -> ~700 cyc of compute cover before the drain).
// Buffer hazards (parity p=j&1): step j stages K(j+2)->kbuf[p] (last read as
// K(j) during step j-1, sealed by that step's barrier+lgkmcnt) and
// V(j+1)->vbuf[1-p] (last read V(j-1) at step j-1); reads K(j+1) from
// kbuf[1-p] and V(j) from vbuf[p] (both staged last step, sealed by last
// barrier's vmcnt). Every write/read pair is separated by exactly one
// __syncthreads. Stage indices wrap &63 (dead data, in-region).
// grid: (bh=64, iblk=16); blockIdx.x=bh keeps XCD = bh%8 (8 heads/XCD in L2).
#define PSTEP_L(JCUR, SCUR, SNXT, KB_ST, KB_RD, VB_ST, VB_RD)                     \
  {                                                                               \
    async16(kg + (((JCUR) + 2) & 63) * 2048, KB_ST);                              \
    async16(vg + (((JCUR) + 1) & 63) * 2048, VB_ST);                              \
    s16x8 kf[4];                                                                  \
    _Pragma("unroll")                                                             \
    for (int c = 0; c < 4; c++)                                                   \
      kf[c] = *reinterpret_cast<const s16x8*>(KB_RD + fro + c * 512);             \
    __builtin_amdgcn_s_setprio(1);                                                \
    SNXT = (f32x16){};                                                            \
    _Pragma("unroll")                                                             \
    for (int c = 0; c < 4; c++)                                                   \
      SNXT = __builtin_amdgcn_mfma_f32_32x32x16_bf16(kf[c], qf[c], SNXT, 0, 0, 0); \
    __builtin_amdgcn_s_setprio(0);                                                \
    unsigned int cc[8];                                                           \
    _Pragma("unroll")                                                             \
    for (int q = 0; q < 4; q++) {                                                 \
      float p0 = EXP2F(SCUR[q * 4 + 0]), p1 = EXP2F(SCUR[q * 4 + 1]);             \
      float p2 = EXP2F(SCUR[q * 4 + 2]), p3 = EXP2F(SCUR[q * 4 + 3]);             \
      ls += (p0 + p1) + (p2 + p3);                                                \
      cc[q * 2 + 0] = pk2bf(p0, p1);                                              \
      cc[q * 2 + 1] = pk2bf(p2, p3);                                              \
    }                                                                             \
    s16x8 pb0, pb1;                                                               \
    make_pb(cc, half, pb0, pb1);                                                  \
    s16x8 vf[4];                                                                  \
    _Pragma("unroll")                                                             \
    for (int c = 0; c < 4; c++)                                                   \
      vf[c] = *reinterpret_cast<const s16x8*>(VB_RD + fro + c * 512);             \
    __builtin_amdgcn_s_setprio(1);                                                \
    ot0 = __builtin_amdgcn_mfma_f32_32x32x16_bf16(vf[0], pb0, ot0, 0, 0, 0);      \
    ot1 = __builtin_amdgcn_mfma_f32_32x32x16_bf16(vf[1], pb0, ot1, 0, 0, 0);      \
    ot0 = __builtin_amdgcn_mfma_f32_32x32x16_bf16(vf[2], pb1, ot0, 0, 0, 0);      \
    ot1 = __builtin_amdgcn_mfma_f32_32x32x16_bf16(vf[3], pb1, ot1, 0, 0, 0);      \
    __builtin_amdgcn_s_setprio(0);                                                \
    __syncthreads();                                                              \
  }

__global__ __launch_bounds__(256, 2) void attn_kernel(
    const u16* __restrict__ Qb, const u16* __restrict__ Kp,
    const u16* __restrict__ Vp, u16* __restrict__ AO) {
  __shared__ __align__(16) u16 kbuf[2][2048];
  __shared__ __align__(16) u16 vbuf[2][2048];
  const int tid = threadIdx.x;
  const int wave = tid >> 6, lane = tid & 63;
  const int l31 = lane & 31, half = lane >> 5;
  const int bh = blockIdx.x, b = bh >> 4, h = bh & 15;
  const int i0 = blockIdx.y * 128 + wave * 32;

  // Q fragments (B-operand). Once per wave.
  const u16* qbase = Qb + (size_t)(b * SEQ + i0 + l31) * INTER + h * HDIM + half * 8;
  s16x8 qf[4];
  #pragma unroll
  for (int c = 0; c < 4; c++) qf[c] = *reinterpret_cast<const s16x8*>(qbase + c * 16);

  // Staging cursors: wave w covers elems [w*512, (w+1)*512) of each 4 KB
  // j-block; HW adds lane*16B -> identity map global<->LDS (fragment
  // addressing unchanged vs the private-load version).
  const u16* kg = Kp + (size_t)bh * (64 * 2048) + wave * 512 + lane * 8;
  const u16* vg = Vp + (size_t)bh * (64 * 2048) + wave * 512 + lane * 8;
  u16* kl0 = &kbuf[0][wave * 512];
  u16* kl1 = &kbuf[1][wave * 512];
  u16* vl0 = &vbuf[0][wave * 512];
  u16* vl1 = &vbuf[1][wave * 512];
  const int fro = lane * 8;                        // + c*512 per fragment

  f32x16 ot0 = {}, ot1 = {};
  float ls = 0.f;

  // Prologue: stage K(0)->kbuf0, K(1)->kbuf1, V(0)->vbuf0; seal; S(0)=QK(K0).
  async16(kg + 0 * 2048, kl0);
  async16(kg + 1 * 2048, kl1);
  async16(vg + 0 * 2048, vl0);
  __syncthreads();                                 // vmcnt(0): stages landed

  f32x16 stA, stB;
  {
    s16x8 kf[4];
    #pragma unroll
    for (int c = 0; c < 4; c++)
      kf[c] = *reinterpret_cast<const s16x8*>(&kbuf[0][fro + c * 512]);
    stA = (f32x16){};
    #pragma unroll
    for (int c = 0; c < 4; c++)
      stA = __builtin_amdgcn_mfma_f32_32x32x16_bf16(kf[c], qf[c], stA, 0, 0, 0);
  }
  __syncthreads();   // lgkmcnt(0): all waves done reading kbuf0 before step 0
                     // overwrites it with K(2)

  // Loop invariant at step j (parity p=j&1): stA=S(j); kbuf[1-p]=K(j+1),
  // vbuf[p]=V(j) (both sealed). Step j stages K(j+2)->kbuf[p], V(j+1)->vbuf[1-p].
  for (int jb = 0; jb < 64; jb += 2) {
    PSTEP_L(jb,     stA, stB, kl0, &kbuf[1][0], vl1, &vbuf[0][0])
    PSTEP_L(jb + 1, stB, stA, kl1, &kbuf[0][0], vl0, &vbuf[1][0])
  }

  ls += __shfl_xor(ls, 32, 64);      // lanes L, L+32 hold complementary j-halves
  float rinv = 1.0f / ls;

  u16* orow = AO + (size_t)(b * SEQ + i0 + l31) * INTER + h * HDIM;
  #pragma unroll
  for (int dt = 0; dt < 2; dt++) {
    const f32x16& o = dt ? ot1 : ot0;
    #pragma unroll
    for (int q = 0; q < 4; q++) {
      uint2 pk;
      pk.x = pk2bf(o[q * 4 + 0] * rinv, o[q * 4 + 1] * rinv);
      pk.y = pk2bf(o[q * 4 + 2] * rinv, o[q * 4 + 3] * rinv);
      *reinterpret_cast<uint2*>(orow + dt * 32 + q * 8 + half * 4) = pk;
    }
  }
}

extern "C" void kernel_launch(void* const* d_in, const int* in_sizes, int n_in,
                              void* d_out, int out_size, void* d_ws, size_t ws_size,
                              hipStream_t stream) {
  const float* features = (const float*)d_in[0];
  const float* W_qkv    = (const float*)d_in[1];
  const float* W_out    = (const float*)d_in[2];
  float* out = (float*)d_out;
  char* w = (char*)d_ws;
  u16* Xb    = (u16*)(w);              // [8192][1024] bf16 features      16 MB
  u16* WqkvT = (u16*)(w + 16777216);   // [3072][1024] bf16 W_qkv^T        6 MB
  u16* WoutT = (u16*)(w + 23068672);   // [1024][1024] bf16 W_out^T        2 MB
  u16* Qb    = (u16*)(w + 25165824);   // [8192][1024] bf16 q (scaled)    16 MB
  u16* Kp    = (u16*)(w + 41943040);   // fragment-packed K               16 MB
  u16* Vp    = (u16*)(w + 58720256);   // fragment-packed V               16 MB
  u16* AO    = Xb;                     // attn out OVERLAYS Xb (Xb dead after
                                       // gemm0; stream-ordered)

  featcast<<<dim3(4096), dim3(256), 0, stream>>>(features, Xb);
  wtrans<<<dim3(1024), dim3(256), 0, stream>>>(W_qkv, W_out, WqkvT, WoutT);
  gemm_bt<0><<<dim3(24, 64), dim3(256), 0, stream>>>(Xb, WqkvT, nullptr, Qb, Kp, Vp,
                                                     DMODEL, 0);
  attn_kernel<<<dim3(64, 16), dim3(256), 0, stream>>>(Qb, Kp, Vp, AO);
  gemm_bt<1><<<dim3(8, 64), dim3(256), 0, stream>>>(AO, WoutT, out, nullptr, nullptr,
                                                    nullptr, INTER, DMODEL);
}

// Round 14
// 280.103 us; speedup vs baseline: 1.0142x; 1.0142x over previous
//
#include <hip/hip_runtime.h>
#include <stdint.h>

#define BB 4
#define SEQ 2048
#define DMODEL 1024
#define NHEAD 16
#define HDIM 64
#define INTER 1024
// attn scale folded into q at GEMM1 epilogue, with log2(e) so softmax is exp2:
// 0.03125 * 1.4426950408889634
#define QSCALE 0.045084220027780106f

#if __has_builtin(__builtin_amdgcn_exp2f)
#define EXP2F(x) __builtin_amdgcn_exp2f(x)
#else
#define EXP2F(x) exp2f(x)
#endif

typedef unsigned short u16;
typedef __attribute__((ext_vector_type(4))) unsigned short u16x4;
typedef __attribute__((ext_vector_type(4))) short s16x4;
typedef __attribute__((ext_vector_type(8))) short s16x8;   // 8 bf16 (4 VGPRs) MFMA A/B frag
typedef __attribute__((ext_vector_type(4))) float f32x4;
typedef __attribute__((ext_vector_type(16))) float f32x16; // 32x32 MFMA C/D frag
typedef __attribute__((ext_vector_type(4))) unsigned int u32x4;

__device__ __forceinline__ u16 f2bf(float f) {
  unsigned int u = __float_as_uint(f);
  u += 0x7FFFu + ((u >> 16) & 1u);   // RNE
  return (u16)(u >> 16);
}

// pack 2 fp32 -> 2 bf16 in one dword (lo = a, hi = b)
#if __has_builtin(__builtin_amdgcn_cvt_pk_bf16_f32)
typedef __attribute__((ext_vector_type(2))) __bf16 bf16x2_t;
__device__ __forceinline__ unsigned int pk2bf(float a, float b) {
  bf16x2_t r = __builtin_amdgcn_cvt_pk_bf16_f32(a, b);
  return *reinterpret_cast<unsigned int*>(&r);
}
#else
__device__ __forceinline__ unsigned int pk2bf(float a, float b) {
  return (unsigned int)f2bf(a) | ((unsigned int)f2bf(b) << 16);
}
#endif

// async global->LDS, 16B per lane; LDS dest is wave-uniform base + lane*16
__device__ __forceinline__ void async16(const u16* g, u16* l) {
  __builtin_amdgcn_global_load_lds((__attribute__((address_space(1))) void*)(void*)(g),
                                   (__attribute__((address_space(3))) void*)(l),
                                   16, 0, 0);
}

// Redistribute P into the two PV B-fragments fully in-register.
// Correctness-verified in the harness (absmax identical to the LDS path).
__device__ __forceinline__ void make_pb(const unsigned int* cc, int half,
                                        s16x8& pb0, s16x8& pb1) {
#if __has_builtin(__builtin_amdgcn_permlane32_swap)
  (void)half;
  auto r02 = __builtin_amdgcn_permlane32_swap(cc[0], cc[2], false, false);
  auto r13 = __builtin_amdgcn_permlane32_swap(cc[1], cc[3], false, false);
  auto r46 = __builtin_amdgcn_permlane32_swap(cc[4], cc[6], false, false);
  auto r57 = __builtin_amdgcn_permlane32_swap(cc[5], cc[7], false, false);
  u32x4 w0 = {(unsigned)r02[0], (unsigned)r13[0], (unsigned)r02[1], (unsigned)r13[1]};
  u32x4 w1 = {(unsigned)r46[0], (unsigned)r57[0], (unsigned)r46[1], (unsigned)r57[1]};
#else
  unsigned x0 = __shfl_xor((int)cc[0], 32, 64), x1 = __shfl_xor((int)cc[1], 32, 64);
  unsigned x2 = __shfl_xor((int)cc[2], 32, 64), x3 = __shfl_xor((int)cc[3], 32, 64);
  unsigned x4 = __shfl_xor((int)cc[4], 32, 64), x5 = __shfl_xor((int)cc[5], 32, 64);
  unsigned x6 = __shfl_xor((int)cc[6], 32, 64), x7 = __shfl_xor((int)cc[7], 32, 64);
  u32x4 w0 = {half ? x2 : cc[0], half ? x3 : cc[1],
              half ? cc[2] : x0, half ? cc[3] : x1};
  u32x4 w1 = {half ? x6 : cc[4], half ? x7 : cc[5],
              half ? cc[6] : x4, half ? cc[7] : x5};
#endif
  pb0 = *reinterpret_cast<s16x8*>(&w0);
  pb1 = *reinterpret_cast<s16x8*>(&w1);
}

// ------------- prep v2a: cast features, 32 B per thread -------------
__global__ __launch_bounds__(256) void featcast(const float* __restrict__ f,
                                                u16* __restrict__ Xb) {
  const int i = (blockIdx.x * 256 + threadIdx.x) * 8;
  f32x4 a = *reinterpret_cast<const f32x4*>(f + i);
  f32x4 b = *reinterpret_cast<const f32x4*>(f + i + 4);
  uint4 o;
  o.x = pk2bf(a[0], a[1]);
  o.y = pk2bf(a[2], a[3]);
  o.z = pk2bf(b[0], b[1]);
  o.w = pk2bf(b[2], b[3]);
  *reinterpret_cast<uint4*>(Xb + i) = o;
}

// ------------- prep v2b: transpose-cast both weights, 64x64 tiles -------------
__global__ __launch_bounds__(256) void wtrans(
    const float* __restrict__ wqkv, const float* __restrict__ wout,
    u16* __restrict__ WqkvT, u16* __restrict__ WoutT) {
  __shared__ u16 tile[64][65];
  int t = blockIdx.x;
  const float* src; u16* dst; int rows, cols, bx, by;
  if (t < 768) {                          // W_qkv: [1024][3072] -> [3072][1024]
    src = wqkv; dst = WqkvT; rows = DMODEL; cols = 3 * INTER;
    bx = t % 48; by = t / 48;
  } else {                                // W_out: [1024][1024] -> [1024][1024]
    t -= 768;
    src = wout; dst = WoutT; rows = INTER; cols = DMODEL;
    bx = t & 15; by = t >> 4;
  }
  const int c0 = bx * 64, r0 = by * 64;
  const int tx = threadIdx.x & 63, ty = threadIdx.x >> 6;
  #pragma unroll
  for (int i = ty; i < 64; i += 4)
    tile[i][tx] = f2bf(src[(size_t)(r0 + i) * cols + c0 + tx]);
  __syncthreads();
  #pragma unroll
  for (int i = ty; i < 64; i += 4)
    dst[(size_t)(c0 + i) * rows + r0 + tx] = tile[tx][i];
}

// ---------------- bf16 GEMM, B-transposed input (round-6, known-good) ----------------
#define GCOMP(ABUF, BBUF)                                                         \
  {                                                                               \
    s16x8 af[4], bf[4];                                                           \
    _Pragma("unroll")                                                             \
    for (int t = 0; t < 4; t++) {                                                 \
      af[t] = *reinterpret_cast<const s16x8*>(&ABUF[(wr + t * 16 + r) * 32 + q8]); \
      bf[t] = *reinterpret_cast<const s16x8*>(&BBUF[(wc + t * 16 + r) * 32 + q8]); \
    }                                                                             \
    _Pragma("unroll")                                                             \
    for (int i = 0; i < 4; i++)                                                   \
      _Pragma("unroll")                                                           \
      for (int j = 0; j < 4; j++)                                                 \
        acc[i][j] = __builtin_amdgcn_mfma_f32_16x16x32_bf16(af[i], bf[j], acc[i][j], 0, 0, 0); \
  }

template <int MODE>
__global__ __launch_bounds__(256, 2) void gemm_bt(
    const u16* __restrict__ A, const u16* __restrict__ BT,
    float* __restrict__ Cf, u16* __restrict__ Qb, u16* __restrict__ Kp,
    u16* __restrict__ Vp, int K, int ldc) {
  __shared__ u16 As[2][128 * 32];
  __shared__ u16 Bs[2][128 * 32];
  const int tid = threadIdx.x;
  const int wave = tid >> 6, lane = tid & 63;
  const int row0 = blockIdx.y * 128, col0 = blockIdx.x * 128;
  const int wr = (wave >> 1) * 64, wc = (wave & 1) * 64;
  const int r = lane & 15, q8 = (lane >> 4) * 8;

  f32x4 acc[4][4] = {};

  const int sRow = lane >> 2, sK = (lane & 3) * 8;
  const u16* Ag0 = A + (size_t)(row0 + wave * 32 + sRow) * K + sK;
  const u16* Ag1 = Ag0 + (size_t)16 * K;
  const u16* Bg0 = BT + (size_t)(col0 + wave * 32 + sRow) * K + sK;
  const u16* Bg1 = Bg0 + (size_t)16 * K;
  u16* Al0a = &As[0][wave * 1024]; u16* Al1a = Al0a + 512;
  u16* Bl0a = &Bs[0][wave * 1024]; u16* Bl1a = Bl0a + 512;
  u16* Al0b = &As[1][wave * 1024]; u16* Al1b = Al0b + 512;
  u16* Bl0b = &Bs[1][wave * 1024]; u16* Bl1b = Bl0b + 512;

  // prologue: stage K-tile 0 into buffer A
  async16(Ag0, Al0a);
  async16(Ag1, Al1a);
  async16(Bg0, Bl0a);
  async16(Bg1, Bl1a);
  __syncthreads();

  for (int k0 = 0; k0 < K; k0 += 64) {
    if (k0 + 32 < K) {
      async16(Ag0 + k0 + 32, Al0b);
      async16(Ag1 + k0 + 32, Al1b);
      async16(Bg0 + k0 + 32, Bl0b);
      async16(Bg1 + k0 + 32, Bl1b);
    }
    GCOMP(As[0], Bs[0])
    __syncthreads();
    if (k0 + 64 < K) {
      async16(Ag0 + k0 + 64, Al0a);
      async16(Ag1 + k0 + 64, Al1a);
      async16(Bg0 + k0 + 64, Bl0a);
      async16(Bg1 + k0 + 64, Bl1a);
    }
    GCOMP(As[1], Bs[1])
    __syncthreads();
  }

  const int quad = lane >> 4;
  #pragma unroll
  for (int i = 0; i < 4; i++) {
    const int n = row0 + wr + i * 16 + quad * 4;   // global row for regs 0..3
    const int b = n >> 11, nn = n & (SEQ - 1);
    #pragma unroll
    for (int j = 0; j < 4; j++) {
      const int gc = col0 + wc + j * 16 + r;       // wave-uniform region
      if (MODE == 1) {
        #pragma unroll
        for (int reg = 0; reg < 4; reg++)
          Cf[(size_t)(n + reg) * ldc + gc] = acc[i][j][reg];
      } else if (gc < INTER) {                     // q: row-major, scaled
        size_t base = (size_t)n * INTER + gc;
        #pragma unroll
        for (int reg = 0; reg < 4; reg++)
          Qb[base + (size_t)reg * INTER] = f2bf(acc[i][j][reg] * QSCALE);
      } else if (gc < 2 * INTER) {                 // k -> Kp packed
        int dim = gc - INTER, h = dim >> 6, d = dim & 63;
        int bh = b * NHEAD + h;
        size_t base = (((size_t)(bh * 64 + (nn >> 5)) * 4 + (d >> 4)) * 64 +
                       ((((d >> 3) & 1) << 5) | (nn & 31))) * 8 + (d & 7);
        #pragma unroll
        for (int reg = 0; reg < 4; reg++)
          Kp[base + reg * 8] = f2bf(acc[i][j][reg]);
      } else {                                     // v -> Vp packed, b64 store
        int dim = gc - 2 * INTER, h = dim >> 6, d = dim & 63;
        int bh = b * NHEAD + h;
        size_t base = ((((size_t)(bh * 64 + (nn >> 5)) * 2 + ((nn >> 4) & 1)) * 2 +
                        (d >> 5)) * 64 +
                       ((((nn >> 3) & 1) << 5) | (d & 31))) * 8 + (nn & 7);
        uint2 pk;
        pk.x = pk2bf(acc[i][j][0], acc[i][j][1]);
        pk.y = pk2bf(acc[i][j][2], acc[i][j][3]);
        *reinterpret_cast<uint2*>(Vp + base) = pk;
      }
    }
  }
}

// ---------------- flash-style attention (round-4 step, 2-wave packing) ----------------
// Third submission of the r11-designed experiment (r12/r13 died to container
// infra failures; source audited -- all components previously passed).
// Single change vs the 94-97us round-4/6 attn: pack TWO independent waves per
// 128-thread block (wave w owns i0 = blockIdx.y*64 + w*32; no shared state,
// no barriers). Occupancy ledger (r0/r2/r4/r11) shows a ~8 WG/CU dispatch cap
// binds 64-thread blocks at 25% occ, below the VGPR limit; 2-wave blocks
// raise resident waves 2->3 per SIMD (VGPR-limited at ~160-168).
// __launch_bounds__(128,3) caps VGPR at ~168 (round-4's cap, no spill;
// WRITE_SIZE 16.4 MB is the tell).
// T15 pipeline: QK(j+1) issues BEFORE softmax(j); K prefetched 2 steps ahead.
// S^T = K.Q^T via 32x32x16 MFMA; q pre-scaled by SCALE*log2e -> p = exp2(s);
// no max-shift. P->PV redistribution in-register via v_permlane32_swap.
// setprio(1) wraps MFMA clusters. grid: (bh=64, 32); blockIdx.x = bh keeps
// the XCD = bh%8 mapping (8 heads = 4 MB K/V per XCD-L2).
#define PSTEP(JCUR, SCUR, SNXT, KNXT, KPF)                                        \
  {                                                                               \
    s16x8 vf[4];                                                                  \
    _Pragma("unroll")                                                             \
    for (int c = 0; c < 4; c++)                                                   \
      vf[c] = *reinterpret_cast<const s16x8*>(vpb + (JCUR) * 2048 + c * 512);     \
    const int jpf = ((JCUR) + 2) & 63;                                            \
    _Pragma("unroll")                                                             \
    for (int c = 0; c < 4; c++)                                                   \
      KPF[c] = *reinterpret_cast<const s16x8*>(kpb + jpf * 2048 + c * 512);       \
    SNXT = (f32x16){};                                                            \
    __builtin_amdgcn_s_setprio(1);                                                \
    _Pragma("unroll")                                                             \
    for (int c = 0; c < 4; c++)                                                   \
      SNXT = __builtin_amdgcn_mfma_f32_32x32x16_bf16(KNXT[c], qf[c], SNXT, 0, 0, 0); \
    __builtin_amdgcn_s_setprio(0);                                                \
    unsigned int cc[8];                                                           \
    _Pragma("unroll")                                                             \
    for (int q = 0; q < 4; q++) {                                                 \
      float p0 = EXP2F(SCUR[q * 4 + 0]), p1 = EXP2F(SCUR[q * 4 + 1]);             \
      float p2 = EXP2F(SCUR[q * 4 + 2]), p3 = EXP2F(SCUR[q * 4 + 3]);             \
      ls += (p0 + p1) + (p2 + p3);                                                \
      cc[q * 2 + 0] = pk2bf(p0, p1);                                              \
      cc[q * 2 + 1] = pk2bf(p2, p3);                                              \
    }                                                                             \
    s16x8 pb0, pb1;                                                               \
    make_pb(cc, half, pb0, pb1);                                                  \
    __builtin_amdgcn_s_setprio(1);                                                \
    ot0 = __builtin_amdgcn_mfma_f32_32x32x16_bf16(vf[0], pb0, ot0, 0, 0, 0);      \
    ot1 = __builtin_amdgcn_mfma_f32_32x32x16_bf16(vf[1], pb0, ot1, 0, 0, 0);      \
    ot0 = __builtin_amdgcn_mfma_f32_32x32x16_bf16(vf[2], pb1, ot0, 0, 0, 0);      \
    ot1 = __builtin_amdgcn_mfma_f32_32x32x16_bf16(vf[3], pb1, ot1, 0, 0, 0);      \
    __builtin_amdgcn_s_setprio(0);                                                \
  }

__global__ __launch_bounds__(128, 3) void attn_kernel(
    const u16* __restrict__ Qb, const u16* __restrict__ Kp,
    const u16* __restrict__ Vp, u16* __restrict__ AO) {
  const int tid = threadIdx.x;
  const int wave = tid >> 6, lane = tid & 63;
  const int l31 = lane & 31, half = lane >> 5;
  const int bh = blockIdx.x, b = bh >> 4, h = bh & 15;
  const int i0 = blockIdx.y * 64 + wave * 32;      // two independent waves

  const u16* qbase = Qb + (size_t)(b * SEQ + i0 + l31) * INTER + h * HDIM + half * 8;
  s16x8 qf[4];
  #pragma unroll
  for (int c = 0; c < 4; c++) qf[c] = *reinterpret_cast<const s16x8*>(qbase + c * 16);

  const u16* kpb = Kp + (size_t)bh * (64 * 4 * 512) + lane * 8;
  const u16* vpb = Vp + (size_t)bh * (64 * 4 * 512) + lane * 8;

  f32x16 ot0 = {}, ot1 = {};
  float ls = 0.f;

  s16x8 kX[4], kY[4];
  #pragma unroll
  for (int c = 0; c < 4; c++)
    kX[c] = *reinterpret_cast<const s16x8*>(kpb + 0 * 2048 + c * 512);
  f32x16 stA = {}, stB;
  #pragma unroll
  for (int c = 0; c < 4; c++)
    stA = __builtin_amdgcn_mfma_f32_32x32x16_bf16(kX[c], qf[c], stA, 0, 0, 0);
  #pragma unroll
  for (int c = 0; c < 4; c++)
    kY[c] = *reinterpret_cast<const s16x8*>(kpb + 1 * 2048 + c * 512);

  for (int jb = 0; jb < 64; jb += 2) {
    PSTEP(jb,     stA, stB, kY, kX)
    PSTEP(jb + 1, stB, stA, kX, kY)
  }

  ls += __shfl_xor(ls, 32, 64);
  float rinv = 1.0f / ls;

  u16* orow = AO + (size_t)(b * SEQ + i0 + l31) * INTER + h * HDIM;
  #pragma unroll
  for (int dt = 0; dt < 2; dt++) {
    const f32x16& o = dt ? ot1 : ot0;
    #pragma unroll
    for (int q = 0; q < 4; q++) {
      uint2 pk;
      pk.x = pk2bf(o[q * 4 + 0] * rinv, o[q * 4 + 1] * rinv);
      pk.y = pk2bf(o[q * 4 + 2] * rinv, o[q * 4 + 3] * rinv);
      *reinterpret_cast<uint2*>(orow + dt * 32 + q * 8 + half * 4) = pk;
    }
  }
}

extern "C" void kernel_launch(void* const* d_in, const int* in_sizes, int n_in,
                              void* d_out, int out_size, void* d_ws, size_t ws_size,
                              hipStream_t stream) {
  const float* features = (const float*)d_in[0];
  const float* W_qkv    = (const float*)d_in[1];
  const float* W_out    = (const float*)d_in[2];
  float* out = (float*)d_out;
  char* w = (char*)d_ws;
  u16* Xb    = (u16*)(w);              // [8192][1024] bf16 features      16 MB
  u16* WqkvT = (u16*)(w + 16777216);   // [3072][1024] bf16 W_qkv^T        6 MB
  u16* WoutT = (u16*)(w + 23068672);   // [1024][1024] bf16 W_out^T        2 MB
  u16* Qb    = (u16*)(w + 25165824);   // [8192][1024] bf16 q (scaled)    16 MB
  u16* Kp    = (u16*)(w + 41943040);   // fragment-packed K               16 MB
  u16* Vp    = (u16*)(w + 58720256);   // fragment-packed V               16 MB
  u16* AO    = Xb;                     // attn out OVERLAYS Xb (Xb dead after
                                       // gemm0; stream-ordered)

  featcast<<<dim3(4096), dim3(256), 0, stream>>>(features, Xb);
  wtrans<<<dim3(1024), dim3(256), 0, stream>>>(W_qkv, W_out, WqkvT, WoutT);
  gemm_bt<0><<<dim3(24, 64), dim3(256), 0, stream>>>(Xb, WqkvT, nullptr, Qb, Kp, Vp,
                                                     DMODEL, 0);
  attn_kernel<<<dim3(64, 32), dim3(128), 0, stream>>>(Qb, Kp, Vp, AO);
  gemm_bt<1><<<dim3(8, 64), dim3(256), 0, stream>>>(AO, WoutT, out, nullptr, nullptr,
                                                    nullptr, INTER, DMODEL);
}